// Round 7
// baseline (45.061 us; speedup 1.0000x reference)
//
#include <hip/hip_runtime.h>
#include <math.h>

// Problem constants
#define B 64
#define CIN 32
#define COUT 32
#define E 16
#define TOPK 4

typedef __attribute__((ext_vector_type(8))) short short8;
typedef __attribute__((ext_vector_type(4))) float f32x4;

// round-to-nearest-even f32 -> bf16 bits
__device__ __forceinline__ unsigned short f2bf(float f) {
    unsigned int u = __float_as_uint(f);
    u += 0x7fffu + ((u >> 16) & 1u);
    return (unsigned short)(u >> 16);
}

// Common XCD swizzle for 1024-block grids: sample b -> XCD (b>>3) in all
// kernels, so xt[b]/cwb[b] stay L2-local between producer and consumer.
__device__ __forceinline__ int swz1024(int o) { return (o & 7) * 128 + (o >> 3); }

// ---------------------------------------------------------------------------
// Kernel 1: NCHW f32 -> padded NHWC bf16 xt[b][h+1][w+1][c] + band-sums.
//   grid = B*16 (b, 4-row band) swizzled, block 256 = 4 waves.
//   Phase 1: float4-coalesced read of the 4x32x64 f32 band (1KB/wave/instr)
//            into LDS, stride-33 rows + (c+w)&31 swizzle (2-way max).
//   Phase 2: transpose out of LDS, bf16 convert, DENSE 1KB short8 row stores,
//            fused band-sum reduce.
// ---------------------------------------------------------------------------
__global__ void __launch_bounds__(256)
transform_gatex(const float* __restrict__ x,
                unsigned short* __restrict__ xt,
                float* __restrict__ bandsum) {
    int blk = swz1024(blockIdx.x);
    int b = blk >> 4, band = blk & 15;
    int h0 = band << 2;
    int t = threadIdx.x;
    int wave = t >> 6, l = t & 63;

    // lds slot(w, r, c) = (w*4 + r)*33 + ((c + w) & 31)
    __shared__ float lds[64 * 4 * 33];

    // ---- phase 1: coalesced read x -> LDS ----
    const float4* x4 = reinterpret_cast<const float4*>(x);
    #pragma unroll
    for (int k = 0; k < 8; k++) {
        int i  = k * 256 + t;          // 0..2047
        int c  = i >> 6;               // wave-uniform (k*4 + wave)
        int r  = (i >> 4) & 3;
        int w4 = i & 15;
        float4 v = x4[(((size_t)(b * 32 + c) * 64 + h0 + r) << 4) + w4];
        int wbase = w4 * 4;
        lds[((wbase + 0) * 4 + r) * 33 + ((c + wbase + 0) & 31)] = v.x;
        lds[((wbase + 1) * 4 + r) * 33 + ((c + wbase + 1) & 31)] = v.y;
        lds[((wbase + 2) * 4 + r) * 33 + ((c + wbase + 2) & 31)] = v.z;
        lds[((wbase + 3) * 4 + r) * 33 + ((c + wbase + 3) & 31)] = v.w;
    }
    __syncthreads();

    // ---- phase 2: transpose, convert, dense store, reduce ----
    int part = l & 3;
    int cg = part * 8;
    int w  = wave * 16 + (l >> 2);

    float racc[8];
    #pragma unroll
    for (int j = 0; j < 8; j++) racc[j] = 0.f;

    #pragma unroll
    for (int r = 0; r < 4; r++) {
        int h = h0 + r;
        short8 ov;
        #pragma unroll
        for (int j = 0; j < 8; j++) {
            float v = lds[(w * 4 + r) * 33 + ((cg + j + w) & 31)];
            racc[j] += v;
            ov[j] = (short)f2bf(v);
        }
        *reinterpret_cast<short8*>(
            xt + (((size_t)b * 66 + (h + 1)) * 66 + (w + 1)) * 32 + cg) = ov;
    }

    // left/right halo: 4 rows x 2 sides x 32 ch = 256 stores, one per thread
    {
        int c = t & 31, side = (t >> 5) & 1, r = t >> 6;
        xt[(((size_t)b * 66 + (h0 + r + 1)) * 66 + side * 65) * 32 + c] = 0;
    }
    // top/bottom halo rows
    if (band == 0) {
        unsigned short* row0 = xt + (size_t)b * 66 * 66 * 32;
        for (int i = t; i < 66 * 32; i += 256) row0[i] = 0;
    }
    if (band == 15) {
        unsigned short* row65 = xt + ((size_t)b * 66 + 65) * 66 * 32;
        for (int i = t; i < 66 * 32; i += 256) row65[i] = 0;
    }

    // reduce racc over the 16 lanes sharing `part` (offsets 4..32)
    #pragma unroll
    for (int off = 4; off < 64; off <<= 1)
        #pragma unroll
        for (int j = 0; j < 8; j++) racc[j] += __shfl_xor(racc[j], off, 64);

    __shared__ float s_rs[4][4][8];   // [wave][part][j]
    if (l < 4) {
        #pragma unroll
        for (int j = 0; j < 8; j++) s_rs[wave][l][j] = racc[j];
    }
    __syncthreads();
    if (t < 32) {
        float s = s_rs[0][t >> 3][t & 7] + s_rs[1][t >> 3][t & 7]
                + s_rs[2][t >> 3][t & 7] + s_rs[3][t >> 3][t & 7];
        bandsum[((size_t)b * 16 + band) * 32 + t] = s;
    }
}

// ---------------------------------------------------------------------------
// Kernel 2: gating (recomputed per block, trivial) + combined weights.
//   grid = B*16 swizzled, block 256.  Each block combines 576 of the 9216
//   weights of its sample, iterating expert_w in NATIVE order (coalesced
//   reads).  q==0 blocks also write cbias / probw / gimpw.
// ---------------------------------------------------------------------------
__global__ void __launch_bounds__(256)
combine_gating(const float* __restrict__ bandsum,
               const float* __restrict__ noise,
               const float* __restrict__ w_gate,
               const float* __restrict__ w_noise,
               const float* __restrict__ expert_w,
               const float* __restrict__ expert_b,
               unsigned short* __restrict__ cwb,
               float* __restrict__ cbias,
               float* __restrict__ probw,
               float* __restrict__ gimpw) {
    int blk = swz1024(blockIdx.x);
    int b = blk >> 4, q = blk & 15;
    int t = threadIdx.x;

    __shared__ float gx[32];
    __shared__ float s_clean[E], s_std[E], s_noisy[E];
    __shared__ float s_tv[TOPK + 1];
    __shared__ float s_grow[E];
    __shared__ float s_g[TOPK];
    __shared__ int   s_gi[TOPK];

    if (t < 32) {
        const float* bp = bandsum + (size_t)b * 16 * 32 + t;
        float s = 0.f;
        #pragma unroll
        for (int j = 0; j < 16; j++) s += bp[j * 32];
        gx[t] = s * (1.f / 4096.f);
    }
    __syncthreads();

    if (t < E) {
        int e = t;
        float s1 = 0.f, s2 = 0.f;
        #pragma unroll
        for (int c = 0; c < CIN; c++) {
            float g = gx[c];
            s1 += g * w_gate[c * E + e];
            s2 += g * w_noise[c * E + e];
        }
        float sp = fmaxf(s2, 0.f) + log1pf(expf(-fabsf(s2)));
        s_clean[e] = s1;
        s_std[e]   = sp + 0.01f;
        s_noisy[e] = s1 + noise[b * E + e] * (sp + 0.01f);
    }
    __syncthreads();

    if (t == 0) {
        float lg[E];
        float m = s_noisy[0];
        #pragma unroll
        for (int e = 1; e < E; e++) m = fmaxf(m, s_noisy[e]);
        float den = 0.f;
        #pragma unroll
        for (int e = 0; e < E; e++) { lg[e] = expf(s_noisy[e] - m); den += lg[e]; }
        float inv = 1.f / den;
        #pragma unroll
        for (int e = 0; e < E; e++) lg[e] *= inv;

        bool used[E];
        #pragma unroll
        for (int e = 0; e < E; e++) { used[e] = false; s_grow[e] = 0.f; }
        float tv[TOPK + 1]; int ti[TOPK + 1];
        for (int r = 0; r < TOPK + 1; r++) {
            float best = -1.f; int bi = 0;
            for (int e = 0; e < E; e++)
                if (!used[e] && lg[e] > best) { best = lg[e]; bi = e; }
            tv[r] = best; ti[r] = bi; used[bi] = true;
            s_tv[r] = best;
        }
        float s4 = tv[0] + tv[1] + tv[2] + tv[3] + 1e-6f;
        for (int r = 0; r < TOPK; r++) {
            float gr = tv[r] / s4;
            s_grow[ti[r]] = gr;
            s_g[r] = gr; s_gi[r] = ti[r];
        }
    }
    __syncthreads();

    if (q == 0 && t < E) {
        const float INV_SQRT2 = 0.70710678118654752f;
        float thr_in = s_tv[TOPK], thr_out = s_tv[TOPK - 1];
        float thr = (s_noisy[t] > thr_in) ? thr_in : thr_out;
        float z = (s_clean[t] - thr) / s_std[t];
        probw[b * E + t] = 0.5f * (1.f + erff(z * INV_SQRT2));
        gimpw[b * E + t] = s_grow[t];
    }

    float g0 = s_g[0], g1 = s_g[1], g2 = s_g[2], g3 = s_g[3];
    int   i0 = s_gi[0], i1 = s_gi[1], i2 = s_gi[2], i3 = s_gi[3];

    // this block's 576-element slice, expert-native order (coalesced reads)
    int lo = q * 576, hi = lo + 576;
    for (int o = lo + t; o < hi; o += 256) {
        int tap = o % 9;
        int cc  = o / 9;               // cout*32 + cin
        float s = g0 * expert_w[i0 * 9216 + o] + g1 * expert_w[i1 * 9216 + o]
                + g2 * expert_w[i2 * 9216 + o] + g3 * expert_w[i3 * 9216 + o];
        cwb[(size_t)b * 9216 + tap * 1024 + cc] = f2bf(s);
    }
    if (q == 0 && t < COUT) {
        cbias[b * COUT + t] = g0 * expert_b[i0 * COUT + t] + g1 * expert_b[i1 * COUT + t]
                            + g2 * expert_b[i2 * COUT + t] + g3 * expert_b[i3 * COUT + t];
    }
}

// ---------------------------------------------------------------------------
// Kernel 3: MFMA conv (9 shifted GEMMs, K=32 per mfma_f32_16x16x32_bf16)
//   + loss reduce in logical block 0.  grid = B*16 swizzled (same map as
//   kernels 1-2 -> xt/cwb reads are L2-local), block 256 = 4 waves.
// ---------------------------------------------------------------------------
__global__ void __launch_bounds__(256, 4)
conv_mfma(const unsigned short* __restrict__ xt,
          const unsigned short* __restrict__ cwb,
          const float* __restrict__ cbias,
          const float* __restrict__ probw,
          const float* __restrict__ gimpw,
          float* __restrict__ y,
          float* __restrict__ loss_out) {
    int blk = swz1024(blockIdx.x);
    int b  = blk >> 4;
    int hb = blk & 15;
    int t  = threadIdx.x;
    int wave = t >> 6, l = t & 63;
    int h  = hb * 4 + wave;            // output row
    int ln = l & 15;                   // n (px) / m (cout) index
    int lk = l >> 4;                   // k group

    const unsigned short* wbase = cwb + (size_t)b * 9216;
    short8 afrag[2][9];
    #pragma unroll
    for (int tap = 0; tap < 9; tap++) {
        #pragma unroll
        for (int ch = 0; ch < 2; ch++) {
            afrag[ch][tap] = *reinterpret_cast<const short8*>(
                wbase + tap * 1024 + (ch * 16 + ln) * 32 + lk * 8);
        }
    }

    float bias0[4], bias1[4];
    #pragma unroll
    for (int r = 0; r < 4; r++) {
        bias0[r] = cbias[b * COUT + lk * 4 + r];
        bias1[r] = cbias[b * COUT + 16 + lk * 4 + r];
    }

    const unsigned short* xb = xt + (size_t)b * 66 * 66 * 32;

    for (int tile = 0; tile < 4; tile++) {
        int w0 = tile * 16;
        f32x4 acc0 = {0.f, 0.f, 0.f, 0.f};
        f32x4 acc1 = {0.f, 0.f, 0.f, 0.f};
        #pragma unroll
        for (int kh = 0; kh < 3; kh++) {
            const unsigned short* xrow = xb + ((size_t)(h + kh) * 66 + w0 + ln) * 32 + lk * 8;
            #pragma unroll
            for (int kw = 0; kw < 3; kw++) {
                short8 bfrag = *reinterpret_cast<const short8*>(xrow + kw * 32);
                acc0 = __builtin_amdgcn_mfma_f32_16x16x32_bf16(afrag[0][kh * 3 + kw], bfrag, acc0, 0, 0, 0);
                acc1 = __builtin_amdgcn_mfma_f32_16x16x32_bf16(afrag[1][kh * 3 + kw], bfrag, acc1, 0, 0, 0);
            }
        }
        #pragma unroll
        for (int r = 0; r < 4; r++) {
            y[((size_t)(b * COUT + lk * 4 + r) * 64 + h) * 64 + w0 + ln]      = acc0[r] + bias0[r];
            y[((size_t)(b * COUT + 16 + lk * 4 + r) * 64 + h) * 64 + w0 + ln] = acc1[r] + bias1[r];
        }
    }

    // ---- loss (logical block 0; probw/gimpw crossed the kernel boundary) ----
    if (blk == 0) {
        __shared__ float s_lv[32];
        if (t < 32) {
            const float* src = (t < 16) ? gimpw : probw;
            int e = t & 15;
            float s = 0.f;
            for (int bb = 0; bb < B; bb++) s += src[bb * E + e];
            s_lv[t] = s;
        }
        __syncthreads();
        if (t == 0) {
            float loss = 0.f;
            for (int pass = 0; pass < 2; pass++) {
                const float* v = s_lv + pass * 16;
                float mean = 0.f;
                for (int e = 0; e < E; e++) mean += v[e];
                mean *= (1.f / E);
                float var = 0.f;
                for (int e = 0; e < E; e++) { float d = v[e] - mean; var += d * d; }
                var *= (1.f / (E - 1));
                loss += var / (mean * mean + 1e-10f);
            }
            loss_out[0] = loss * 0.01f;
        }
    }
}

// ---------------------------------------------------------------------------
extern "C" void kernel_launch(void* const* d_in, const int* in_sizes, int n_in,
                              void* d_out, int out_size, void* d_ws, size_t ws_size,
                              hipStream_t stream) {
    const float* x        = (const float*)d_in[0];
    const float* noise    = (const float*)d_in[1];
    const float* w_gate   = (const float*)d_in[2];
    const float* w_noise  = (const float*)d_in[3];
    const float* expert_w = (const float*)d_in[4];
    const float* expert_b = (const float*)d_in[5];

    float* y    = (float*)d_out;
    float* loss = y + (size_t)B * COUT * 64 * 64;

    char* ws = (char*)d_ws;
    unsigned short* xt      = (unsigned short*)(ws);             // 17,842,176 B
    float*          bandsum = (float*)(ws + 17842176);           //    131,072 B
    unsigned short* cwb     = (unsigned short*)(ws + 17973248);  //  1,179,648 B
    float*          cbias   = (float*)(ws + 19152896);           //      8,192 B
    float*          probw   = (float*)(ws + 19161088);           //      4,096 B
    float*          gimpw   = (float*)(ws + 19165184);           //      4,096 B

    transform_gatex<<<B * 16, 256, 0, stream>>>(x, xt, bandsum);
    combine_gating<<<B * 16, 256, 0, stream>>>(bandsum, noise, w_gate, w_noise,
                                               expert_w, expert_b, cwb, cbias,
                                               probw, gimpw);
    conv_mfma<<<B * 16, 256, 0, stream>>>(xt, cwb, cbias, probw, gimpw, y, loss);
}

// Round 8
// 37.945 us; speedup vs baseline: 1.1875x; 1.1875x over previous
//
#include <hip/hip_runtime.h>
#include <math.h>

// Problem constants
#define B 64
#define CIN 32
#define COUT 32
#define E 16
#define TOPK 4

typedef __attribute__((ext_vector_type(8))) short short8;
typedef __attribute__((ext_vector_type(4))) float f32x4;

// round-to-nearest-even f32 -> bf16 bits
__device__ __forceinline__ unsigned short f2bf(float f) {
    unsigned int u = __float_as_uint(f);
    u += 0x7fffu + ((u >> 16) & 1u);
    return (unsigned short)(u >> 16);
}

// XCD swizzle for 1024-block grids: sample b -> XCD (b>>3) in all kernels.
__device__ __forceinline__ int swz1024(int o) { return (o & 7) * 128 + (o >> 3); }

// LDS channel swizzle: spreads the per-w' channel groups over 8 bank-starts
// so B-frag ds_read_b128 across 16 consecutive w' is 2-way (free).
__device__ __forceinline__ int cswz(int wp, int c) {
    return c ^ (((wp >> 2) & 3) << 3);
}

// ---------------------------------------------------------------------------
// Kernel 1: band sums of x (for the gating mean).  grid B*16 swizzled,
//   block 256 = 4 waves.  Wave-coalesced float4 reads (4KB contiguous per
//   wave per step), butterfly reduce, lane-0 scalar stores.  No LDS.
// ---------------------------------------------------------------------------
__global__ void __launch_bounds__(256)
bandsum_kernel(const float* __restrict__ x, float* __restrict__ bandsum) {
    int blk = swz1024(blockIdx.x);
    int b = blk >> 4, band = blk & 15, h0 = band << 2;
    int t = threadIdx.x, wave = t >> 6, l = t & 63;
    const float4* x4 = reinterpret_cast<const float4*>(x);

    float racc[8];
    #pragma unroll
    for (int k = 0; k < 8; k++) {
        int c = k * 4 + wave;
        float4 v = x4[(((size_t)(b * 32 + c) * 64 + h0 + (l >> 4)) << 4) + (l & 15)];
        racc[k] = (v.x + v.y) + (v.z + v.w);
    }
    #pragma unroll
    for (int off = 1; off < 64; off <<= 1)
        #pragma unroll
        for (int k = 0; k < 8; k++) racc[k] += __shfl_xor(racc[k], off, 64);
    if (l == 0) {
        #pragma unroll
        for (int k = 0; k < 8; k++)
            bandsum[((size_t)b * 16 + band) * 32 + k * 4 + wave] = racc[k];
    }
}

// ---------------------------------------------------------------------------
// Kernel 2 (fused): per-block gating recompute + weight combine into LDS +
//   inline NCHW->NHWC bf16 transpose of the x slab into LDS + MFMA conv.
//   grid = B*16 swizzled, block 256 = 4 waves (one output row each).
//   No xt / cwb intermediates in global memory at all.
// ---------------------------------------------------------------------------
__global__ void __launch_bounds__(256)
conv_fused(const float* __restrict__ x,
           const float* __restrict__ bandsum,
           const float* __restrict__ noise,
           const float* __restrict__ w_gate,
           const float* __restrict__ w_noise,
           const float* __restrict__ expert_w,
           const float* __restrict__ expert_b,
           float* __restrict__ probw,
           float* __restrict__ gimpw,
           float* __restrict__ y) {
    int blk = swz1024(blockIdx.x);
    int b = blk >> 4, band = blk & 15, h0 = band << 2;
    int t = threadIdx.x, wave = t >> 6, l = t & 63;
    int ln = l & 15, lk = l >> 4;

    __shared__ unsigned short sx[6 * 66 * 32];   // x slab, bf16, 25,344 B
    __shared__ unsigned short cw[9 * 1024];      // combined weights, 18,432 B
    __shared__ float gx[32], s_bias[32];
    __shared__ float s_clean[E], s_std[E], s_noisy[E], s_lg[E];
    __shared__ float s_tv[TOPK + 1], s_g[TOPK];
    __shared__ int   s_gi[TOPK];

    // ---- gating: gate_x from bandsum ----
    if (t < 32) {
        const float* bp = bandsum + (size_t)b * 16 * 32 + t;
        float s = 0.f;
        #pragma unroll
        for (int j = 0; j < 16; j++) s += bp[j * 32];
        gx[t] = s * (1.f / 4096.f);
    }
    __syncthreads();
    if (t < E) {
        float s1 = 0.f, s2 = 0.f;
        #pragma unroll
        for (int c = 0; c < CIN; c++) {
            float g = gx[c];
            s1 += g * w_gate[c * E + t];
            s2 += g * w_noise[c * E + t];
        }
        float sp = fmaxf(s2, 0.f) + log1pf(expf(-fabsf(s2)));
        s_clean[t] = s1;
        s_std[t]   = sp + 0.01f;
        s_noisy[t] = s1 + noise[b * E + t] * (sp + 0.01f);
    }
    __syncthreads();
    if (t < E) {
        float m = s_noisy[0];
        #pragma unroll
        for (int e = 1; e < E; e++) m = fmaxf(m, s_noisy[e]);
        float den = 0.f;
        #pragma unroll
        for (int e = 0; e < E; e++) den += expf(s_noisy[e] - m);
        s_lg[t] = expf(s_noisy[t] - m) / den;
    }
    __syncthreads();
    // rank-based stable top-k (parallel, no serial selection loop)
    if (t < E) {
        float v = s_lg[t]; int rank = 0;
        #pragma unroll
        for (int j = 0; j < E; j++) {
            float u = s_lg[j];
            rank += (u > v) || (u == v && j < t);
        }
        if (rank <= TOPK) s_tv[rank] = v;
        if (rank <  TOPK) s_gi[rank] = t;
    }
    __syncthreads();
    if (t < TOPK) {
        float s4 = s_tv[0] + s_tv[1] + s_tv[2] + s_tv[3] + 1e-6f;
        s_g[t] = s_tv[t] / s4;
    }
    __syncthreads();

    // loss inputs, written once per sample (band 0 blocks)
    if (band == 0 && t < E) {
        float s4 = s_tv[0] + s_tv[1] + s_tv[2] + s_tv[3] + 1e-6f;
        float v = s_lg[t]; int rank = 0;
        #pragma unroll
        for (int j = 0; j < E; j++) {
            float u = s_lg[j];
            rank += (u > v) || (u == v && j < t);
        }
        gimpw[b * E + t] = (rank < TOPK) ? v / s4 : 0.f;
        const float INV_SQRT2 = 0.70710678118654752f;
        float thr_in = s_tv[TOPK], thr_out = s_tv[TOPK - 1];
        float thr = (s_noisy[t] > thr_in) ? thr_in : thr_out;
        float z = (s_clean[t] - thr) / s_std[t];
        probw[b * E + t] = 0.5f * (1.f + erff(z * INV_SQRT2));
    }

    // ---- x slab loader: coalesced f32 reads, transposed bf16 LDS writes ----
    const float4* x4 = reinterpret_cast<const float4*>(x);
    #pragma unroll
    for (int k = 0; k < 12; k++) {
        int i = k * 256 + t;                // 0..3071
        int rr = i >> 9, c = (i >> 4) & 31, w4 = i & 15;
        int gr = h0 - 1 + rr;
        float4 v = {0.f, 0.f, 0.f, 0.f};
        if ((unsigned)gr < 64u)
            v = x4[(((size_t)(b * 32 + c) * 64 + gr) << 4) + w4];
        float vv[4] = {v.x, v.y, v.z, v.w};
        #pragma unroll
        for (int j = 0; j < 4; j++) {
            int wp = 1 + w4 * 4 + j;
            sx[(rr * 66 + wp) * 32 + cswz(wp, c)] = f2bf(vv[j]);
        }
    }
    // w' = 0 / 65 halo columns (cswz(0,c)=cswz(65,c)=c)
    for (int i = t; i < 384; i += 256) {
        int rr = i >> 6, rem = i & 63, side = rem >> 5, c = rem & 31;
        sx[(rr * 66 + side * 65) * 32 + c] = 0;
    }
    // ---- weight combine into LDS (expert_w is L2/L3-resident) ----
    {
        const float* e0 = expert_w + s_gi[0] * 9216;
        const float* e1 = expert_w + s_gi[1] * 9216;
        const float* e2 = expert_w + s_gi[2] * 9216;
        const float* e3 = expert_w + s_gi[3] * 9216;
        float g0 = s_g[0], g1 = s_g[1], g2 = s_g[2], g3 = s_g[3];
        #pragma unroll
        for (int k = 0; k < 36; k++) {
            int o = k * 256 + t;            // expert-native order (coalesced)
            int cc = o / 9, tap = o - cc * 9;
            float s = g0 * e0[o] + g1 * e1[o] + g2 * e2[o] + g3 * e3[o];
            cw[tap * 1024 + cc] = f2bf(s);
        }
        if (t < 32)
            s_bias[t] = g0 * expert_b[s_gi[0] * 32 + t] + g1 * expert_b[s_gi[1] * 32 + t]
                      + g2 * expert_b[s_gi[2] * 32 + t] + g3 * expert_b[s_gi[3] * 32 + t];
    }
    __syncthreads();

    // ---- MFMA conv: 9 shifted GEMMs, K=32 per mfma_f32_16x16x32_bf16 ----
    short8 afrag[2][9];
    #pragma unroll
    for (int tap = 0; tap < 9; tap++)
        #pragma unroll
        for (int ch = 0; ch < 2; ch++)
            afrag[ch][tap] = *reinterpret_cast<const short8*>(
                &cw[tap * 1024 + (ch * 16 + ln) * 32 + lk * 8]);

    float bias0[4], bias1[4];
    #pragma unroll
    for (int r = 0; r < 4; r++) {
        bias0[r] = s_bias[lk * 4 + r];
        bias1[r] = s_bias[16 + lk * 4 + r];
    }

    int h = h0 + wave;
    for (int tile = 0; tile < 4; tile++) {
        int w0 = tile * 16;
        f32x4 acc0 = {0.f, 0.f, 0.f, 0.f};
        f32x4 acc1 = {0.f, 0.f, 0.f, 0.f};
        #pragma unroll
        for (int kh = 0; kh < 3; kh++) {
            int rr = wave + kh;
            #pragma unroll
            for (int kw = 0; kw < 3; kw++) {
                int wp = w0 + ln + kw;
                short8 bfrag = *reinterpret_cast<const short8*>(
                    &sx[(rr * 66 + wp) * 32 + cswz(wp, lk * 8)]);
                acc0 = __builtin_amdgcn_mfma_f32_16x16x32_bf16(afrag[0][kh * 3 + kw], bfrag, acc0, 0, 0, 0);
                acc1 = __builtin_amdgcn_mfma_f32_16x16x32_bf16(afrag[1][kh * 3 + kw], bfrag, acc1, 0, 0, 0);
            }
        }
        #pragma unroll
        for (int r = 0; r < 4; r++) {
            y[((size_t)(b * COUT + lk * 4 + r) * 64 + h) * 64 + w0 + ln]      = acc0[r] + bias0[r];
            y[((size_t)(b * COUT + 16 + lk * 4 + r) * 64 + h) * 64 + w0 + ln] = acc1[r] + bias1[r];
        }
    }
}

// ---------------------------------------------------------------------------
// Kernel 3: loss from per-sample prob / gate rows.  1 block, 64 threads.
// ---------------------------------------------------------------------------
__global__ void loss_kernel(const float* __restrict__ probw,
                            const float* __restrict__ gimpw,
                            float* __restrict__ loss_out) {
    __shared__ float s_lv[32];
    int t = threadIdx.x;
    if (t < 32) {
        const float* src = (t < 16) ? gimpw : probw;
        int e = t & 15;
        float s = 0.f;
        for (int bb = 0; bb < B; bb++) s += src[bb * E + e];
        s_lv[t] = s;
    }
    __syncthreads();
    if (t == 0) {
        float loss = 0.f;
        for (int pass = 0; pass < 2; pass++) {
            const float* v = s_lv + pass * 16;
            float mean = 0.f;
            for (int e = 0; e < E; e++) mean += v[e];
            mean *= (1.f / E);
            float var = 0.f;
            for (int e = 0; e < E; e++) { float d = v[e] - mean; var += d * d; }
            var *= (1.f / (E - 1));
            loss += var / (mean * mean + 1e-10f);
        }
        loss_out[0] = loss * 0.01f;
    }
}

// ---------------------------------------------------------------------------
extern "C" void kernel_launch(void* const* d_in, const int* in_sizes, int n_in,
                              void* d_out, int out_size, void* d_ws, size_t ws_size,
                              hipStream_t stream) {
    const float* x        = (const float*)d_in[0];
    const float* noise    = (const float*)d_in[1];
    const float* w_gate   = (const float*)d_in[2];
    const float* w_noise  = (const float*)d_in[3];
    const float* expert_w = (const float*)d_in[4];
    const float* expert_b = (const float*)d_in[5];

    float* y    = (float*)d_out;
    float* loss = y + (size_t)B * COUT * 64 * 64;

    char* ws = (char*)d_ws;
    float* bands  = (float*)(ws);            // 131,072 B
    float* probw  = (float*)(ws + 131072);   //   4,096 B
    float* gimpw  = (float*)(ws + 135168);   //   4,096 B

    bandsum_kernel<<<B * 16, 256, 0, stream>>>(x, bands);
    conv_fused<<<B * 16, 256, 0, stream>>>(x, bands, noise, w_gate, w_noise,
                                           expert_w, expert_b, probw, gimpw, y);
    loss_kernel<<<1, 64, 0, stream>>>(probw, gimpw, loss);
}